// Round 10
// baseline (411.529 us; speedup 1.0000x reference)
//
#include <hip/hip_runtime.h>
#include <cstdint>

#define N_NODES 100000
#define N_EDGES 1600000
#define R_REL   5
#define NBASIS  2
#define B_START 512
#define NBUCK   256
#define BUCK_SZ 391       // 256 * 391 = 100096 >= 100000
#define EPB     6250      // edges per block in cnt/scat (256 * 6250 = 1.6M)
#define STAGE_CAP 7000    // bucket edge-count mean 6256, sd ~79 -> 9.4 sigma

__device__ __forceinline__ unsigned short f2bf(float f) {
    unsigned u = __float_as_uint(f);
    unsigned r = (u + 0x7FFF + ((u >> 16) & 1)) >> 16;  // RNE
    return (unsigned short)r;
}

// ---------------- scatter-free CSR build ----------------

// Pass A: per-block 256-bucket histogram (LDS), coalesced table write.
__global__ __launch_bounds__(256) void k_cntb(
    const int* __restrict__ ei, int* __restrict__ bhist) {
    __shared__ int lh[NBUCK];
    int tid = threadIdx.x;
    lh[tid] = 0;
    __syncthreads();
    int base = blockIdx.x * EPB;
    for (int j = tid; j < EPB; j += 256) {
        int dst = ei[N_EDGES + base + j];
        atomicAdd(&lh[dst / BUCK_SZ], 1);
    }
    __syncthreads();
    bhist[blockIdx.x * NBUCK + tid] = lh[tid];
}

// Pass B: single block; thread b owns bucket b.
__global__ __launch_bounds__(256) void k_scanb(
    int* __restrict__ bhist, int* __restrict__ bbase) {
    int b = threadIdx.x;
    int tot = 0;
    for (int i = 0; i < NBUCK; i += 8) {
        int v0 = bhist[(i + 0) * NBUCK + b], v1 = bhist[(i + 1) * NBUCK + b];
        int v2 = bhist[(i + 2) * NBUCK + b], v3 = bhist[(i + 3) * NBUCK + b];
        int v4 = bhist[(i + 4) * NBUCK + b], v5 = bhist[(i + 5) * NBUCK + b];
        int v6 = bhist[(i + 6) * NBUCK + b], v7 = bhist[(i + 7) * NBUCK + b];
        tot += v0 + v1 + v2 + v3 + v4 + v5 + v6 + v7;
    }
    __shared__ int s[NBUCK];
    s[b] = tot;
    __syncthreads();
    for (int o = 1; o < NBUCK; o <<= 1) {
        int v = (b >= o) ? s[b - o] : 0;
        __syncthreads();
        s[b] += v;
        __syncthreads();
    }
    int base = s[b] - tot;  // exclusive
    bbase[b] = base;
    if (b == NBUCK - 1) bbase[NBUCK] = s[NBUCK - 1];
    int run = base;
    for (int i = 0; i < NBUCK; i += 8) {
        int v0 = bhist[(i + 0) * NBUCK + b], v1 = bhist[(i + 1) * NBUCK + b];
        int v2 = bhist[(i + 2) * NBUCK + b], v3 = bhist[(i + 3) * NBUCK + b];
        int v4 = bhist[(i + 4) * NBUCK + b], v5 = bhist[(i + 5) * NBUCK + b];
        int v6 = bhist[(i + 6) * NBUCK + b], v7 = bhist[(i + 7) * NBUCK + b];
        bhist[(i + 0) * NBUCK + b] = run; run += v0;
        bhist[(i + 1) * NBUCK + b] = run; run += v1;
        bhist[(i + 2) * NBUCK + b] = run; run += v2;
        bhist[(i + 3) * NBUCK + b] = run; run += v3;
        bhist[(i + 4) * NBUCK + b] = run; run += v4;
        bhist[(i + 5) * NBUCK + b] = run; run += v5;
        bhist[(i + 6) * NBUCK + b] = run; run += v6;
        bhist[(i + 7) * NBUCK + b] = run; run += v7;
    }
}

// Pass C: deterministic bucket scatter (run-clustered line-dense writes).
// record = src | et<<17 | dst_local<<20
__global__ __launch_bounds__(256) void k_scat(
    const int* __restrict__ ei, const int* __restrict__ et,
    const int* __restrict__ bhist, int* __restrict__ arena) {
    __shared__ int lc[NBUCK];
    int tid = threadIdx.x;
    lc[tid] = bhist[blockIdx.x * NBUCK + tid];
    __syncthreads();
    int base = blockIdx.x * EPB;
    for (int j = tid; j < EPB; j += 256) {
        int e   = base + j;
        int src = ei[e];
        int dst = ei[N_EDGES + e];
        int t   = et[e];
        int bk  = dst / BUCK_SZ;
        int dl  = dst - bk * BUCK_SZ;
        int pos = atomicAdd(&lc[bk], 1);
        arena[pos] = src | (t << 17) | (dl << 20);
    }
}

// Pass D: one block per bucket; emits globally dst-sorted edge streams:
// pk_m = src|et<<17, pk_nv = 1/cnt(dst,et), pk_dst = dst. All coalesced.
__global__ __launch_bounds__(256) void k_build(
    const int* __restrict__ arena, const int* __restrict__ bbase,
    int* __restrict__ pk_m, float* __restrict__ pk_nv,
    int* __restrict__ pk_dst) {
    __shared__ int deg5[BUCK_SZ * R_REL];
    __shared__ int loff[BUCK_SZ + 1];
    __shared__ int cur[BUCK_SZ];
    __shared__ int stg[STAGE_CAP];
    int b = blockIdx.x, tid = threadIdx.x;
    int base = bbase[b], end = bbase[b + 1];
    int count = end - base;
    for (int i = tid; i < BUCK_SZ * R_REL; i += 256) deg5[i] = 0;
    __syncthreads();
    for (int i = tid; i < count; i += 256) {
        int r  = arena[base + i];
        int dl = ((unsigned)r) >> 20;
        int t  = (r >> 17) & 7;
        atomicAdd(&deg5[dl * R_REL + t], 1);
    }
    __syncthreads();
    if (tid == 0) {
        int run = 0;
        for (int dl = 0; dl < BUCK_SZ; dl++) {
            loff[dl] = run;
            run += deg5[dl * R_REL + 0] + deg5[dl * R_REL + 1] +
                   deg5[dl * R_REL + 2] + deg5[dl * R_REL + 3] +
                   deg5[dl * R_REL + 4];
        }
        loff[BUCK_SZ] = run;
    }
    __syncthreads();
    for (int dl = tid; dl < BUCK_SZ; dl += 256) cur[dl] = loff[dl];
    __syncthreads();
    for (int i = tid; i < count; i += 256) {
        int r  = arena[base + i];
        int dl = ((unsigned)r) >> 20;
        int rk = atomicAdd(&cur[dl], 1);
        if (rk < STAGE_CAP) stg[rk] = r;
    }
    __syncthreads();
    for (int i = tid; i < count; i += 256) {
        int r   = stg[i < STAGE_CAP ? i : STAGE_CAP - 1];
        int src = r & 0x1FFFF;
        int t   = (r >> 17) & 7;
        int dl  = ((unsigned)r) >> 20;
        int c   = deg5[dl * R_REL + t];
        pk_m[base + i]   = src | (t << 17);
        pk_nv[base + i]  = 1.0f / (float)(c > 0 ? c : 1);
        pk_dst[base + i] = b * BUCK_SZ + dl;
    }
}

// ---------------- per-layer node transform ---------------------------------
// y5[r][n][c] = bf16( comp[r,0]*(h@B0) + comp[r,1]*(h@B1) )   (5 planes)
// h_out := h@root + bias  (edge kernel atomically adds messages into it).
// TIN: apply tanh to h_in on read (h buffers hold PRE-tanh states).
// If sav != nullptr: groups 0..511 also save tanh(h_in[start[b]]) (race-free:
// h_in and h_out are distinct ping-pong buffers).

template <int IN, bool TIN>
__global__ __launch_bounds__(256) void k_xform(
    const float* __restrict__ h_in, float* __restrict__ h_out,
    unsigned short* __restrict__ y5, const float* __restrict__ basis,
    const float* __restrict__ root, const float* __restrict__ biasL,
    const float* __restrict__ compL, const int* __restrict__ start,
    float* __restrict__ sav) {
    int tid  = threadIdx.x;
    int lane = tid & 31;
    int sub  = tid >> 5;
    int g    = blockIdx.x * 8 + sub;   // 1024 blocks * 8 = 8192 groups
    if (IN == 32 && sav != nullptr && g < B_START) {
        int row = start[g];
        sav[g * 32 + lane] = tanhf(h_in[row * 32 + lane]);
    }
    float w0[IN], w1[IN], wr[IN];
#pragma unroll
    for (int i = 0; i < IN; i++) {
        w0[i] = basis[i * 32 + lane];
        w1[i] = basis[IN * 32 + i * 32 + lane];
        wr[i] = root[i * 32 + lane];
    }
    float c0[R_REL], c1[R_REL];
#pragma unroll
    for (int r = 0; r < R_REL; r++) {
        c0[r] = compL[r * NBASIS + 0];
        c1[r] = compL[r * NBASIS + 1];
    }
    float bv = biasL[lane];
    for (int n = g; n < N_NODES; n += 8192) {
        float hn = (lane < IN) ? h_in[n * IN + lane] : 0.f;
        if (TIN) hn = tanhf(hn);
        float a0 = 0.f, a1 = 0.f, ar = bv;
#pragma unroll
        for (int i = 0; i < IN; i++) {
            float v = __shfl(hn, i, 32);
            a0 += v * w0[i];
            a1 += v * w1[i];
            ar += v * wr[i];
        }
#pragma unroll
        for (int r = 0; r < R_REL; r++)
            y5[(size_t)r * N_NODES * 32 + n * 32 + lane] = f2bf(c0[r] * a0 + c1[r] * a1);
        h_out[n * 32 + lane] = ar;
    }
}

// ---------------- flat segmented edge sweep --------------------------------
// Half-wave takes 32 consecutive (dst-sorted) edges: zero padding, no off[].
// In-register accumulate while dst unchanged; flush via float atomicAdd
// (~3 flushes per 32-run). h holds root+bias baseline; tanh applied by
// consumers.

__global__ __launch_bounds__(256) void k_edge(
    const unsigned short* __restrict__ y5, float* __restrict__ h,
    const int* __restrict__ pk_m, const float* __restrict__ pk_nv,
    const int* __restrict__ pk_dst) {
    int tid  = threadIdx.x;
    int lane = tid & 31;
    int sub  = tid >> 5;
    int run  = blockIdx.x * 8 + sub;        // 50000 runs of 32 edges
    int base = run * 32;
    if (base >= N_EDGES) return;
    int idx = base + lane;
    int   m  = pk_m[idx];
    float nv = pk_nv[idx];
    int   d  = pk_dst[idx];

    float acc = 0.f;
    int dcur = __shfl(d, 0, 32);
#pragma unroll
    for (int j = 0; j < 32; j += 8) {
        int mm[8];
#pragma unroll
        for (int q = 0; q < 8; q++) mm[q] = __shfl(m, j + q, 32);
        unsigned short uu[8];
#pragma unroll
        for (int q = 0; q < 8; q++) {
            unsigned r = ((unsigned)mm[q] >> 17) * N_NODES + (mm[q] & 0x1FFFF);
            uu[q] = y5[(size_t)r * 32 + lane];
        }
        float val[8];
#pragma unroll
        for (int q = 0; q < 8; q++)
            val[q] = __shfl(nv, j + q, 32) *
                     __uint_as_float((unsigned)uu[q] << 16);
#pragma unroll
        for (int q = 0; q < 8; q++) {
            int dj = __shfl(d, j + q, 32);
            if (dj != dcur) {
                atomicAdd(&h[(size_t)dcur * 32 + lane], acc);
                acc = 0.f;
                dcur = dj;
            }
            acc += val[q];
        }
    }
    atomicAdd(&h[(size_t)dcur * 32 + lane], acc);
}

// ---------------- final-layer save + MLP head ----------------

__global__ void k_saveT(const float* __restrict__ h, const int* __restrict__ start,
                        float* __restrict__ sav) {
    int t = blockIdx.x * blockDim.x + threadIdx.x;
    if (t < B_START * 32) {
        int b = t >> 5, ln = t & 31;
        sav[t] = tanhf(h[start[b] * 32 + ln]);
    }
}

__global__ __launch_bounds__(128) void k_mlp(
    const float* __restrict__ sav, const float* __restrict__ w1,
    const float* __restrict__ b1, const float* __restrict__ w2,
    const float* __restrict__ b2, float* __restrict__ out) {
    __shared__ float cvec[128];
    __shared__ float hb[128];
    __shared__ float lg[8];
    int b = blockIdx.x, t = threadIdx.x;
    cvec[t] = sav[(t >> 5) * (B_START * 32) + b * 32 + (t & 31)];
    __syncthreads();
    float a = b1[t];
#pragma unroll 8
    for (int k = 0; k < 128; k++) a += cvec[k] * w1[k * 128 + t];
    hb[t] = fmaxf(a, 0.f);
    __syncthreads();
    if (t < 5) {
        float a2 = b2[t];
        for (int k = 0; k < 128; k++) a2 += hb[k] * w2[k * 5 + t];
        lg[t] = a2;
    }
    __syncthreads();
    if (t < 5) {
        float m = lg[0];
        for (int j = 1; j < 5; j++) m = fmaxf(m, lg[j]);
        float s = 0.f;
        for (int j = 0; j < 5; j++) s += expf(lg[j] - m);
        out[b * 5 + t] = lg[t] - m - logf(s);
    }
}

// ---------------- launch ----------------

extern "C" void kernel_launch(void* const* d_in, const int* in_sizes, int n_in,
                              void* d_out, int out_size, void* d_ws, size_t ws_size,
                              hipStream_t stream) {
    const float* x      = (const float*)d_in[0];
    const int*   ei     = (const int*)d_in[1];
    const int*   etype  = (const int*)d_in[2];
    const int*   start  = (const int*)d_in[3];
    const float* basis0 = (const float*)d_in[4];
    const float* comp0  = (const float*)d_in[5];
    const float* root0  = (const float*)d_in[6];
    const float* bias0  = (const float*)d_in[7];
    const float* basis  = (const float*)d_in[8];
    const float* comp   = (const float*)d_in[9];
    const float* root   = (const float*)d_in[10];
    const float* bias   = (const float*)d_in[11];
    const float* w1     = (const float*)d_in[12];
    const float* b1     = (const float*)d_in[13];
    const float* w2     = (const float*)d_in[14];
    const float* b2     = (const float*)d_in[15];
    float* out = (float*)d_out;

    char* p = (char*)d_ws;
    auto alloc = [&](size_t bytes) -> void* {
        void* r = (void*)p;
        p += (bytes + 255) & ~(size_t)255;
        return r;
    };
    int*            bhist  = (int*)alloc((size_t)NBUCK * NBUCK * 4);
    int*            bbase  = (int*)alloc((NBUCK + 1) * 4);
    int*            arena  = (int*)alloc((size_t)N_EDGES * 4);
    int*            pk_m   = (int*)alloc((size_t)N_EDGES * 4);
    float*          pk_nv  = (float*)alloc((size_t)N_EDGES * 4);
    int*            pk_dst = (int*)alloc((size_t)N_EDGES * 4);
    float*          hA     = (float*)alloc((size_t)N_NODES * 32 * 4);
    float*          hB     = (float*)alloc((size_t)N_NODES * 32 * 4);
    unsigned short* y5     = (unsigned short*)alloc((size_t)R_REL * N_NODES * 32 * 2);
    float*          sav    = (float*)alloc(4 * B_START * 32 * 4);

    k_cntb<<<NBUCK, 256, 0, stream>>>(ei, bhist);
    k_scanb<<<1, 256, 0, stream>>>(bhist, bbase);
    k_scat<<<NBUCK, 256, 0, stream>>>(ei, etype, bhist, arena);
    k_build<<<NBUCK, 256, 0, stream>>>(arena, bbase, pk_m, pk_nv, pk_dst);

    int nbEdge = (N_EDGES / 32 + 7) / 8;  // 6250 blocks
    // layer 0 (in=4): x -> hA
    k_xform<4, false><<<1024, 256, 0, stream>>>(x, hA, y5, basis0, root0,
                                                bias0, comp0, start, nullptr);
    k_edge<<<nbEdge, 256, 0, stream>>>(y5, hA, pk_m, pk_nv, pk_dst);
    // layers 1..3 (in=32), ping-pong hA/hB; save fused into next xform
    float* hin = hA;
    float* hout = hB;
    for (int l = 0; l < 3; l++) {
        k_xform<32, true><<<1024, 256, 0, stream>>>(
            hin, hout, y5, basis + (size_t)l * 2048, root + (size_t)l * 1024,
            bias + l * 32, comp + l * 10, start, sav + l * 16384);
        k_edge<<<nbEdge, 256, 0, stream>>>(y5, hout, pk_m, pk_nv, pk_dst);
        float* tmp = hin; hin = hout; hout = tmp;
    }
    k_saveT<<<64, 256, 0, stream>>>(hin, start, sav + 3 * 16384);

    k_mlp<<<B_START, 128, 0, stream>>>(sav, w1, b1, w2, b2, out);
}